// Round 15
// baseline (594.018 us; speedup 1.0000x reference)
//
#include <hip/hip_runtime.h>
#include <hip/hip_bf16.h>
#include <cstdint>
#include <cstddef>

#define N_NODES 100000
#define N_EDGES 500000
#define F_IN    512
#define NHID    128
#define KP1     20000
#define KP2     4000
#define KP3     800
#define GDIM    32
#define NCLS    3
#define HISTB   128   // tail blocks fused into the GEMMs for edge histogram
#define RDB     64    // tail blocks fused into the GEMMs for prev-layer readout
#define RELB    768   // tail blocks fused into pool dispatch for edge relabel

typedef __attribute__((ext_vector_type(8))) short bf16x8;
typedef __attribute__((ext_vector_type(4))) float f32x4;

// ---------- helpers ----------
static __device__ __forceinline__ unsigned enc_f(float f) {
  unsigned u = __float_as_uint(f);
  return (u & 0x80000000u) ? ~u : (u | 0x80000000u);   // monotonic float->uint
}
static __device__ __forceinline__ float dec_f(unsigned u) {
  unsigned v = (u & 0x80000000u) ? (u & 0x7FFFFFFFu) : ~u;
  return __uint_as_float(v);
}
static __device__ __forceinline__ unsigned short f2bf(float f) {  // RNE f32->bf16
  unsigned u = __float_as_uint(f);
  return (unsigned short)((u + 0x7FFFu + ((u >> 16) & 1u)) >> 16);
}
static __device__ __forceinline__ unsigned pk2(float a, float b) {
  return (unsigned)f2bf(a) | ((unsigned)f2bf(b) << 16);
}
static __device__ __forceinline__ float bf2f(unsigned short v) {
  return __uint_as_float(((unsigned)v) << 16);
}

// edge-histogram tail (shared by the GEMM): grid-stride atomics into cnt
static __device__ __forceinline__ void hist_tail(int hb, int t, int nthreads,
                                                 const int* __restrict__ dst,
                                                 const int* __restrict__ ev,
                                                 int* __restrict__ cnt) {
  for (int e = hb * nthreads + t; e < N_EDGES; e += HISTB * nthreads) {
    if (ev && !ev[e]) continue;
    atomicAdd(cnt + dst[e], 1);
  }
}

// ---------- W prep: bf16-transposed weights for ALL three layers ----------
__global__ __launch_bounds__(256) void wt_prep(const float* __restrict__ w1l,
                                               const float* __restrict__ w1r,
                                               const float* __restrict__ w2l,
                                               const float* __restrict__ w2r,
                                               const float* __restrict__ w3l,
                                               const float* __restrict__ w3r,
                                               unsigned short* __restrict__ Wt,
                                               unsigned short* __restrict__ Wt2,
                                               unsigned short* __restrict__ Wt3,
                                               int* __restrict__ cnt0,
                                               unsigned* __restrict__ hist) {
  __shared__ unsigned short T[128][130];
  int blk = blockIdx.x;
  int t = threadIdx.x;
  if (blk == 0) hist[t] = 0u;
  for (int i = blk * 256 + t; i < N_NODES; i += (int)gridDim.x * 256) cnt0[i] = 0;

  const float* W;
  unsigned short* Wo;
  int mat, k0, KW;
  if (blk < 8) {
    mat = blk >> 2; k0 = (blk & 3) * 128; KW = 512;
    W = mat ? w1r : w1l; Wo = Wt;
  } else if (blk < 10) {
    mat = blk - 8; k0 = 0; KW = 128;
    W = mat ? w2r : w2l; Wo = Wt2;
  } else {
    mat = blk - 10; k0 = 0; KW = 128;
    W = mat ? w3r : w3l; Wo = Wt3;
  }
  for (int q = 0; q < 64; ++q) {
    int idx = q * 256 + t;
    int r = idx >> 7, c = idx & 127;
    T[r][c] = f2bf(W[(size_t)(k0 + r) * 128 + c]);
  }
  __syncthreads();
  int nn = t & 127;
  int kc = (t >> 7) * 64;
  for (int j8 = 0; j8 < 8; ++j8) {
    uint4 w;
    int kb = kc + j8 * 8;
    w.x = (unsigned)T[kb + 0][nn] | ((unsigned)T[kb + 1][nn] << 16);
    w.y = (unsigned)T[kb + 2][nn] | ((unsigned)T[kb + 3][nn] << 16);
    w.z = (unsigned)T[kb + 4][nn] | ((unsigned)T[kb + 5][nn] << 16);
    w.w = (unsigned)T[kb + 6][nn] | ((unsigned)T[kb + 7][nn] << 16);
    *reinterpret_cast<uint4*>(Wo + ((size_t)(mat * 128 + nn) * KW + k0 + kb)) = w;
  }
}

// ---------- dual GEMM via MFMA, NO-LDS / NO-BARRIER variant ----------
// Round-15 theory: the ~125us invariance across 5 schedule variants is the
// 2-full-drain-barriers-per-K-step convoy (782 blocks all co-resident ->
// dispatch time ~= single-block time). Here each of the 8 waves owns 16
// DISTINCT rows (A read once per block), loads A fragments straight from
// global into registers and streams all 16 B fragments from L2-resident Wt.
// Zero __syncthreads in the GEMM path; waves fully independent.
// Fragment contents and (k0,kk) MFMA order identical to the LDS version ->
// bit-identical outputs.
__global__ __launch_bounds__(512) void gemm_mfma(const void* __restrict__ Ain, int aBf16,
                                                 const unsigned short* __restrict__ Wt,
                                                 unsigned short* __restrict__ O1b,
                                                 unsigned short* __restrict__ Gb,
                                                 int n, int K, int nbA,
                                                 const int* __restrict__ edst,
                                                 const int* __restrict__ eev,
                                                 int* __restrict__ cnt,
                                                 const unsigned short* __restrict__ Hprev,
                                                 int kprev,
                                                 unsigned* __restrict__ maxaccP,
                                                 float* __restrict__ sumaccP) {
  __shared__ float red[4][128];               // readout-tail scratch only
  const int t = threadIdx.x;
  if ((int)blockIdx.x >= nbA + HISTB) {
    // previous-layer readout tail (64 blocks); acc was zeroed in select/scanB(prev)
    int hb = blockIdx.x - nbA - HISTB;
    int f = t & 127, rg = t >> 7;
    float m = -INFINITY, s = 0.f;
    for (int r = hb * 4 + rg; r < kprev; r += RDB * 4) {
      float v = bf2f(Hprev[(size_t)r * 128 + f]);
      m = fmaxf(m, v); s += v;
    }
    red[rg][f] = m;
    __syncthreads();
    if (t < 128) {
      float mm = fmaxf(fmaxf(red[0][t], red[1][t]), fmaxf(red[2][t], red[3][t]));
      atomicMax(maxaccP + t, enc_f(mm));
    }
    __syncthreads();
    red[rg][f] = s;
    __syncthreads();
    if (t < 128) {
      float ss = red[0][t] + red[1][t] + red[2][t] + red[3][t];
      atomicAdd(sumaccP + t, ss);
    }
    return;
  }
  if ((int)blockIdx.x >= nbA) {
    hist_tail(blockIdx.x - nbA, t, 512, edst, eev, cnt);
    return;
  }
  const int wg = t >> 6;          // wave 0..7 : owns rows [bm+wg*16, +16)
  const int lane = t & 63;
  const int l15 = lane & 15, l4 = lane >> 4;
  const int bm = blockIdx.x * 128;
  const int row = bm + wg * 16 + l15;     // the A row this lane reads
  const bool rv = row < n;

  f32x4 zero = {0.f, 0.f, 0.f, 0.f};
  f32x4 acc[16];                  // 16 col-tiles of 16 (M=16 x N=256)
#pragma unroll
  for (int i = 0; i < 16; ++i) acc[i] = zero;

  const float* apf = (const float*)Ain + (size_t)row * K;
  const unsigned short* apb = (const unsigned short*)Ain + (size_t)row * K;

  for (int k0 = 0; k0 < K; k0 += 64) {
#pragma unroll
    for (int kk = 0; kk < 2; ++kk) {
      const int kb = k0 + kk * 32 + l4 * 8;   // 8 consecutive k per lane
      bf16x8 af;
      if (aBf16) {
        uint4 w = make_uint4(0u, 0u, 0u, 0u);
        if (rv) w = *reinterpret_cast<const uint4*>(apb + kb);
        af = *reinterpret_cast<const bf16x8*>(&w);
      } else {
        float4 v0 = make_float4(0.f, 0.f, 0.f, 0.f), v1 = v0;
        if (rv) {
          v0 = *reinterpret_cast<const float4*>(apf + kb);
          v1 = *reinterpret_cast<const float4*>(apf + kb + 4);
        }
        uint4 w;
        w.x = pk2(v0.x, v0.y); w.y = pk2(v0.z, v0.w);
        w.z = pk2(v1.x, v1.y); w.w = pk2(v1.z, v1.w);
        af = *reinterpret_cast<const bf16x8*>(&w);
      }
#pragma unroll
      for (int fn = 0; fn < 16; ++fn) {
        int col = fn * 16 + l15;
        bf16x8 bfr = *reinterpret_cast<const bf16x8*>(Wt + ((size_t)col * K + kb));
        acc[fn] = __builtin_amdgcn_mfma_f32_16x16x32_bf16(af, bfr, acc[fn], 0, 0, 0);
      }
    }
  }

#pragma unroll
  for (int fn = 0; fn < 16; ++fn) {
    int colg = fn * 16 + l15;
    int col = colg & 127;
    int row0 = bm + wg * 16 + l4 * 4;
#pragma unroll
    for (int r2 = 0; r2 < 4; ++r2) {
      int gr = row0 + r2;
      if (gr < n) {
        unsigned short bv = f2bf(acc[fn][r2]);
        if (colg < 128) O1b[(size_t)gr * 128 + col] = bv;
        else            Gb [(size_t)gr * 128 + col] = bv;
      }
    }
  }
}

// ---------- CSR build: multi-dispatch path (large n) ----------
__global__ void scan1(const int* __restrict__ cnt, int n,
                      int* __restrict__ incl, int* __restrict__ bsum) {
  __shared__ int sh[256];
  int t = threadIdx.x, i = blockIdx.x * 256 + t;
  int v = (i < n) ? cnt[i] : 0;
  sh[t] = v; __syncthreads();
  for (int o = 1; o < 256; o <<= 1) {
    int a = (t >= o) ? sh[t - o] : 0;
    __syncthreads(); sh[t] += a; __syncthreads();
  }
  if (i < n) incl[i] = sh[t];
  if (t == 255) bsum[blockIdx.x] = sh[255];
}

__global__ void scan2(int* __restrict__ bsum, int nb) {
  __shared__ int sh[512];
  int t = threadIdx.x;
  int v = (t < nb) ? bsum[t] : 0;
  sh[t] = v; __syncthreads();
  for (int o = 1; o < 512; o <<= 1) {
    int a = (t >= o) ? sh[t - o] : 0;
    __syncthreads(); sh[t] += a; __syncthreads();
  }
  if (t < nb) bsum[t] = sh[t] - v;   // exclusive
}

__global__ void scan3(const int* __restrict__ cnt, const int* __restrict__ incl,
                      const int* __restrict__ bsum, int n,
                      int* __restrict__ rowstart, int* __restrict__ ptr,
                      int* __restrict__ cnt_next, int n_next) {
  int i = blockIdx.x * 256 + threadIdx.x;
  if (i < n_next) cnt_next[i] = 0;
  if (i >= n) return;
  int excl = incl[i] - cnt[i] + bsum[blockIdx.x];
  rowstart[i] = excl; ptr[i] = excl;
  if (i == n - 1) rowstart[n] = excl + cnt[i];
}

// ---------- CSR offsets: single-block path (small n only) ----------
__global__ __launch_bounds__(1024) void csr_scan_one(const int* __restrict__ cnt, int n,
                                                     int* __restrict__ rowstart,
                                                     int* __restrict__ ptr,
                                                     int* __restrict__ cnt_next, int n_next) {
  __shared__ int sg[1024];
  const int t = threadIdx.x;
  for (int i = t; i < n_next; i += 1024) cnt_next[i] = 0;
  const int chunk = (n + 1023) >> 10;
  const int i0 = t * chunk;
  const int i1 = (i0 + chunk < n) ? i0 + chunk : n;
  int c = 0;
  for (int i = i0; i < i1; ++i) c += cnt[i];
  sg[t] = c;
  __syncthreads();
  for (int o = 1; o < 1024; o <<= 1) {
    int a = (t >= o) ? sg[t - o] : 0;
    __syncthreads();
    sg[t] += a;
    __syncthreads();
  }
  int excl = sg[t] - c;
  for (int i = i0; i < i1; ++i) {
    rowstart[i] = excl; ptr[i] = excl;
    excl += cnt[i];
  }
  if (t == 1023) rowstart[n] = sg[1023];
}

__global__ void scatter_csr(const int* __restrict__ src, const int* __restrict__ dst,
                            const int* __restrict__ ev, int* __restrict__ ptr,
                            int* __restrict__ csr_src) {
  int e = blockIdx.x * 256 + threadIdx.x;
  if (e >= N_EDGES) return;
  if (ev && !ev[e]) return;
  int p = atomicAdd(ptr + dst[e], 1);
  csr_src[p] = src[e];
}

// canonical order inside each segment -> deterministic f32 sums
__global__ void segsort(const int* __restrict__ rowstart, int* __restrict__ csr, int n) {
  int i = blockIdx.x * 256 + threadIdx.x;
  if (i >= n) return;
  int b = rowstart[i], e = rowstart[i + 1];
  for (int j = b + 1; j < e; ++j) {
    int v = csr[j], k = j - 1;
    while (k >= b && csr[k] > v) { csr[k + 1] = csr[k]; --k; }
    csr[k + 1] = v;
  }
}

// ---------- fused aggregation + GCN xw (bf16; 4 independent gathers in flight) ----------
__global__ void agg_fin(const unsigned short* __restrict__ X1b, const int* __restrict__ rowstart,
                        const int* __restrict__ csr, const float* __restrict__ bias,
                        const float* __restrict__ gw,
                        unsigned short* __restrict__ Gb, float* __restrict__ xw, int n) {
  int wid = (blockIdx.x * 256 + threadIdx.x) >> 6;
  if (wid >= n) return;
  int lane = threadIdx.x & 63;
  int b = rowstart[wid], e = rowstart[wid + 1];
  float sx = 0.f, sy = 0.f;
  int p = b;
  for (; p + 3 < e; p += 4) {
    int s0 = csr[p], s1 = csr[p + 1], s2 = csr[p + 2], s3 = csr[p + 3];
    unsigned v0 = *reinterpret_cast<const unsigned*>(X1b + (size_t)s0 * 128 + lane * 2);
    unsigned v1 = *reinterpret_cast<const unsigned*>(X1b + (size_t)s1 * 128 + lane * 2);
    unsigned v2 = *reinterpret_cast<const unsigned*>(X1b + (size_t)s2 * 128 + lane * 2);
    unsigned v3 = *reinterpret_cast<const unsigned*>(X1b + (size_t)s3 * 128 + lane * 2);
    sx += bf2f((unsigned short)(v0 & 0xFFFFu)); sy += bf2f((unsigned short)(v0 >> 16));
    sx += bf2f((unsigned short)(v1 & 0xFFFFu)); sy += bf2f((unsigned short)(v1 >> 16));
    sx += bf2f((unsigned short)(v2 & 0xFFFFu)); sy += bf2f((unsigned short)(v2 >> 16));
    sx += bf2f((unsigned short)(v3 & 0xFFFFu)); sy += bf2f((unsigned short)(v3 >> 16));
  }
  for (; p < e; ++p) {
    int s0 = csr[p];
    unsigned v0 = *reinterpret_cast<const unsigned*>(X1b + (size_t)s0 * 128 + lane * 2);
    sx += bf2f((unsigned short)(v0 & 0xFFFFu));
    sy += bf2f((unsigned short)(v0 >> 16));
  }
  int c = e - b; if (c < 1) c = 1;
  float inv = 1.f / (float)c;
  float2 bi = *reinterpret_cast<const float2*>(bias + lane * 2);
  unsigned gv = *reinterpret_cast<const unsigned*>(Gb + (size_t)wid * 128 + lane * 2);
  float gx = bf2f((unsigned short)(gv & 0xFFFFu));
  float gy = bf2f((unsigned short)(gv >> 16));
  float2 o = make_float2(fmaxf(sx * inv + bi.x + gx, 0.f),
                         fmaxf(sy * inv + bi.y + gy, 0.f));
  *reinterpret_cast<unsigned*>(Gb + (size_t)wid * 128 + lane * 2) = pk2(o.x, o.y);
  float2 gwv = *reinterpret_cast<const float2*>(gw + lane * 2);
  float s = o.x * gwv.x + o.y * gwv.y;
  for (int off = 32; off; off >>= 1) s += __shfl_down(s, off);
  if (lane == 0) xw[wid] = s;
}

// ---------- GCN score (4-deep unroll; also initializes top-k radix state) ----------
__global__ void gcn_score_csr(const float* __restrict__ xw, const int* __restrict__ rowstart,
                              const int* __restrict__ csr, const int* __restrict__ cnt,
                              const float* __restrict__ gb,
                              float* __restrict__ score, unsigned* __restrict__ keys, int n,
                              unsigned* __restrict__ state, int kout) {
  int i = blockIdx.x * 256 + threadIdx.x;
  if (i == 0) { state[0] = 0u; state[1] = (unsigned)kout; }
  if (i >= n) return;
  int b = rowstart[i], e = rowstart[i + 1];
  float di = rsqrtf((float)(e - b) + 1.f);
  float s = 0.f;
  int p = b;
  for (; p + 3 < e; p += 4) {
    int s0 = csr[p], s1 = csr[p + 1], s2 = csr[p + 2], s3 = csr[p + 3];
    float x0 = xw[s0], x1 = xw[s1], x2 = xw[s2], x3 = xw[s3];
    float c0 = (float)cnt[s0], c1 = (float)cnt[s1];
    float c2 = (float)cnt[s2], c3 = (float)cnt[s3];
    s += x0 * rsqrtf(c0 + 1.f);
    s += x1 * rsqrtf(c1 + 1.f);
    s += x2 * rsqrtf(c2 + 1.f);
    s += x3 * rsqrtf(c3 + 1.f);
  }
  for (; p < e; ++p) {
    int s0 = csr[p];
    s += xw[s0] * rsqrtf((float)cnt[s0] + 1.f);
  }
  float sc = s * di + xw[i] * di * di + gb[0];
  score[i] = sc;
  keys[i] = enc_f(sc);
}

// ---------- top-k radix select, multi-block path (large n) ----------
__global__ void topk_hist(const unsigned* __restrict__ keys, int n,
                          const unsigned* __restrict__ state, unsigned mask, int shift,
                          unsigned* __restrict__ hist) {
  __shared__ unsigned h[256];
  int t = threadIdx.x;
  h[t] = 0u;
  __syncthreads();
  unsigned pref = state[0];
  for (int i = blockIdx.x * 256 + t; i < n; i += gridDim.x * 256) {
    unsigned k = keys[i];
    if ((k & mask) == pref) atomicAdd(&h[(k >> shift) & 0xFFu], 1u);
  }
  __syncthreads();
  unsigned hv = h[t];
  if (hv) atomicAdd(&hist[t], hv);
}

__global__ void topk_pick(unsigned* state, unsigned* hist, int shift) {
  __shared__ unsigned h[256], a[256];
  int t = threadIdx.x;
  unsigned hv = hist[t];
  hist[t] = 0;                      // clear for next pass
  h[t] = hv;
  __syncthreads();
  a[t] = h[255 - t];                // reversed for suffix-sum
  __syncthreads();
  for (int o = 1; o < 256; o <<= 1) {
    unsigned v = (t >= o) ? a[t - o] : 0u;
    __syncthreads();
    a[t] += v;
    __syncthreads();
  }
  unsigned krem = state[1];
  unsigned Sb  = a[255 - t];
  unsigned Sb1 = (t == 255) ? 0u : a[255 - (t + 1)];
  if (Sb >= krem && Sb1 < krem) {
    state[0] |= ((unsigned)t) << shift;
    state[1] = krem - Sb1;
  }
}

// ---------- deterministic compaction (rank assignment), multi-block path ----------
__global__ void scanA(const unsigned* __restrict__ keys, int n,
                      const unsigned* __restrict__ state,
                      unsigned* __restrict__ pgt, unsigned* __restrict__ peq) {
  __shared__ unsigned sg[256], se[256];
  int t = threadIdx.x;
  int i = blockIdx.x * 256 + t;
  unsigned kth = state[0];
  unsigned g = 0, e = 0;
  if (i < n) { unsigned k = keys[i]; g = (k > kth); e = (k == kth); }
  sg[t] = g; se[t] = e;
  __syncthreads();
  for (int s = 128; s; s >>= 1) {
    if (t < s) { sg[t] += sg[t + s]; se[t] += se[t + s]; }
    __syncthreads();
  }
  if (t == 0) { pgt[blockIdx.x] = sg[0]; peq[blockIdx.x] = se[0]; }
}

// also zeroes this layer's readout accumulators (runs before readout)
__global__ void scanB(unsigned* pgt, unsigned* peq, int nb,
                      unsigned* __restrict__ maxacc, float* __restrict__ sumacc) {
  __shared__ unsigned a[512], b[512];
  int t = threadIdx.x;
  if (t < 128) { maxacc[t] = 0u; sumacc[t] = 0.f; }
  unsigned og = (t < nb) ? pgt[t] : 0u;
  unsigned oe = (t < nb) ? peq[t] : 0u;
  a[t] = og; b[t] = oe;
  __syncthreads();
  for (int o = 1; o < 512; o <<= 1) {
    unsigned av = (t >= o) ? a[t - o] : 0u;
    unsigned bv = (t >= o) ? b[t - o] : 0u;
    __syncthreads();
    a[t] += av; b[t] += bv;
    __syncthreads();
  }
  if (t < nb) { pgt[t] = a[t] - og; peq[t] = b[t] - oe; }   // exclusive
}

__global__ void scanC(const unsigned* __restrict__ keys, int n,
                      const unsigned* __restrict__ state,
                      const unsigned* __restrict__ pgt, const unsigned* __restrict__ peq,
                      int K, int* __restrict__ rank) {
  __shared__ unsigned sg[256], se[256];
  int t = threadIdx.x;
  int i = blockIdx.x * 256 + t;
  unsigned kth = state[0], krem = state[1];
  unsigned g = 0, e = 0;
  if (i < n) { unsigned k = keys[i]; g = (k > kth); e = (k == kth); }
  sg[t] = g; se[t] = e;
  __syncthreads();
  for (int o = 1; o < 256; o <<= 1) {
    unsigned av = (t >= o) ? sg[t - o] : 0u;
    unsigned bv = (t >= o) ? se[t - o] : 0u;
    __syncthreads();
    sg[t] += av; se[t] += bv;
    __syncthreads();
  }
  if (i < n) {
    int r = -1;
    unsigned n_gt = (unsigned)K - krem;
    if (g) r = (int)(pgt[blockIdx.x] + sg[t] - 1);
    else if (e) {
      unsigned pe = peq[blockIdx.x] + se[t] - 1;
      if (pe < krem) r = (int)(n_gt + pe);
    }
    rank[i] = r;
  }
}

// ---------- single-block top-k + rank (small n ONLY) ----------
__global__ __launch_bounds__(1024) void select_one(const unsigned* __restrict__ keys, int n,
                                                   int K, int* __restrict__ rank,
                                                   unsigned* __restrict__ maxacc,
                                                   float* __restrict__ sumacc) {
  __shared__ unsigned h[256], a[256];
  __shared__ unsigned sg[1024], se[1024];
  __shared__ unsigned s_pref, s_krem;
  const int t = threadIdx.x;
  if (t < 128) { maxacc[t] = 0u; sumacc[t] = 0.f; }
  if (t == 0) { s_pref = 0u; s_krem = (unsigned)K; }
  __syncthreads();

#pragma unroll
  for (int p = 0; p < 4; ++p) {
    const int shift = 24 - 8 * p;
    const unsigned mask = (p == 0) ? 0u : (0xFFFFFFFFu << (shift + 8));
    if (t < 256) h[t] = 0u;
    __syncthreads();
    unsigned pref = s_pref;
    for (int i = t; i < n; i += 1024) {
      unsigned k = keys[i];
      if ((k & mask) == pref) atomicAdd(&h[(k >> shift) & 0xFFu], 1u);
    }
    __syncthreads();
    if (t < 256) a[t] = h[255 - t];   // reversed for suffix-sum
    __syncthreads();
    for (int o = 1; o < 256; o <<= 1) {
      unsigned v = (t >= o && t < 256) ? a[t - o] : 0u;
      __syncthreads();
      if (t < 256) a[t] += v;
      __syncthreads();
    }
    unsigned krem = s_krem;
    __syncthreads();
    if (t < 256) {
      unsigned Sb  = a[255 - t];
      unsigned Sb1 = (t == 255) ? 0u : a[255 - (t + 1)];
      if (Sb >= krem && Sb1 < krem) {
        s_pref |= ((unsigned)t) << shift;
        s_krem = krem - Sb1;
      }
    }
    __syncthreads();
  }

  // rank assignment, index order (contiguous per-thread chunks)
  const unsigned kth = s_pref;
  const unsigned krem = s_krem;
  const unsigned n_gt = (unsigned)K - krem;
  const int chunk = (n + 1023) >> 10;
  const int i0 = t * chunk;
  const int i1 = (i0 + chunk < n) ? i0 + chunk : n;
  unsigned cg = 0, ce = 0;
  for (int i = i0; i < i1; ++i) {
    unsigned k = keys[i];
    cg += (k > kth); ce += (k == kth);
  }
  sg[t] = cg; se[t] = ce;
  __syncthreads();
  for (int o = 1; o < 1024; o <<= 1) {
    unsigned ag = (t >= o) ? sg[t - o] : 0u;
    unsigned ae = (t >= o) ? se[t - o] : 0u;
    __syncthreads();
    sg[t] += ag; se[t] += ae;
    __syncthreads();
  }
  unsigned rg = sg[t] - cg;   // exclusive prefix of > count
  unsigned re = se[t] - ce;   // exclusive prefix of == count
  for (int i = i0; i < i1; ++i) {
    unsigned k = keys[i];
    int r = -1;
    if (k > kth) {
      r = (int)(rg++);
    } else if (k == kth) {
      unsigned pe = re++;
      if (pe < krem) r = (int)(n_gt + pe);
    }
    rank[i] = r;
  }
}

// ---------- pooling (bf16 G -> bf16 Hout) + (tail) edge relabel ----------
__global__ void pool_rel(const unsigned short* __restrict__ Gb, const float* __restrict__ score,
                         const int* __restrict__ rank, unsigned short* __restrict__ Houtb, int n,
                         int nbP, int mode,
                         const int* __restrict__ ei,
                         int* __restrict__ src2, int* __restrict__ dst2,
                         int* __restrict__ ev2) {
  const int t = threadIdx.x;
  if ((int)blockIdx.x >= nbP) {
    int hb = blockIdx.x - nbP;
    if (mode == 0) {
      for (int e = hb * 256 + t; e < N_EDGES; e += RELB * 256) {
        int s = ei[e], d = ei[N_EDGES + e];
        int rs = rank[s], rd = rank[d];
        int valid = (rs >= 0) & (rd >= 0);
        src2[e] = rs > 0 ? rs : 0;
        dst2[e] = rd > 0 ? rd : 0;
        ev2[e] = valid;
      }
    } else if (mode == 1) {
      for (int e = hb * 256 + t; e < N_EDGES; e += RELB * 256) {
        if (!ev2[e]) continue;
        int s = src2[e], d = dst2[e];
        int rs = rank[s], rd = rank[d];
        int valid = (rs >= 0) & (rd >= 0);
        src2[e] = rs > 0 ? rs : 0;
        dst2[e] = rd > 0 ? rd : 0;
        ev2[e] = valid;
      }
    }
    return;
  }
  int gid = blockIdx.x * 256 + t;
  int i = gid >> 5;
  if (i >= n) return;
  int r = rank[i];
  if (r < 0) return;
  int q = gid & 31;
  float tv = tanhf(score[i]);
  uint2 v = *reinterpret_cast<const uint2*>(Gb + (size_t)i * 128 + q * 4);
  float a0 = bf2f((unsigned short)(v.x & 0xFFFFu)) * tv;
  float a1 = bf2f((unsigned short)(v.x >> 16)) * tv;
  float a2 = bf2f((unsigned short)(v.y & 0xFFFFu)) * tv;
  float a3 = bf2f((unsigned short)(v.y >> 16)) * tv;
  uint2 o = make_uint2(pk2(a0, a1), pk2(a2, a3));
  *reinterpret_cast<uint2*>(Houtb + (size_t)r * 128 + q * 4) = o;
}

// ---------- graph readout (bf16 H; used for the LAST layer only) ----------
__global__ void readout_reduce(const unsigned short* __restrict__ Hb, int k,
                               unsigned* __restrict__ maxacc, float* __restrict__ sumacc) {
  int f = threadIdx.x;   // 128
  float m = -INFINITY, s = 0.f;
  for (int r = blockIdx.x; r < k; r += gridDim.x) {
    float v = bf2f(Hb[(size_t)r * 128 + f]);
    m = fmaxf(m, v);
    s += v;
  }
  atomicMax(maxacc + f, enc_f(m));
  atomicAdd(sumacc + f, s);
}

// ---------- head MLP (decodes per-layer readout accumulators directly) ----------
__global__ void head_kernel(const unsigned* __restrict__ maxacc3,
                            const float* __restrict__ sumacc3,
                            const float* __restrict__ lw1, const float* __restrict__ lb1,
                            const float* __restrict__ lw2, const float* __restrict__ lb2,
                            const float* __restrict__ lw3, const float* __restrict__ lb3,
                            float* __restrict__ out) {
  __shared__ float g[256];
  __shared__ float t1[128];
  __shared__ float t2[32];
  int t = threadIdx.x;
  float v;
  if (t < 128) {
    v = dec_f(maxacc3[t]) + dec_f(maxacc3[128 + t]) + dec_f(maxacc3[256 + t]);
  } else {
    int f = t - 128;
    v = sumacc3[f] * (1.f / (float)KP1) + sumacc3[128 + f] * (1.f / (float)KP2) +
        sumacc3[256 + f] * (1.f / (float)KP3);
  }
  g[t] = v;
  __syncthreads();
  if (t < 128) {
    float s = lb1[t];
    for (int j = 0; j < 256; ++j) s += g[j] * lw1[j * 128 + t];
    t1[t] = fmaxf(s, 0.f);
  }
  __syncthreads();
  if (t < 32) {
    float s = lb2[t];
    for (int j = 0; j < 128; ++j) s += t1[j] * lw2[j * 32 + t];
    float v2 = fmaxf(s, 0.f);
    t2[t] = v2;
    out[t] = v2;                // features
  }
  __syncthreads();
  if (t < NCLS) {
    float s = lb3[t];
    for (int j = 0; j < 32; ++j) s += t2[j] * lw3[j * 3 + t];
    out[32 + t] = s;            // logits
  }
}

// ---------- launch ----------
extern "C" void kernel_launch(void* const* d_in, const int* in_sizes, int n_in_,
                              void* d_out, int out_size, void* d_ws, size_t ws_size,
                              hipStream_t stream) {
  (void)in_sizes; (void)n_in_; (void)out_size; (void)ws_size;
  const float* x   = (const float*)d_in[0];
  const int*   ei  = (const int*)d_in[1];
  const float* w1l = (const float*)d_in[2];
  const float* b1l = (const float*)d_in[3];
  const float* w1r = (const float*)d_in[4];
  const float* g1w = (const float*)d_in[5];
  const float* g1b = (const float*)d_in[6];
  const float* w2l = (const float*)d_in[7];
  const float* b2l = (const float*)d_in[8];
  const float* w2r = (const float*)d_in[9];
  const float* g2w = (const float*)d_in[10];
  const float* g2b = (const float*)d_in[11];
  const float* w3l = (const float*)d_in[12];
  const float* b3l = (const float*)d_in[13];
  const float* w3r = (const float*)d_in[14];
  const float* g3w = (const float*)d_in[15];
  const float* g3b = (const float*)d_in[16];
  const float* lw1 = (const float*)d_in[17];
  const float* lb1 = (const float*)d_in[18];
  const float* lw2 = (const float*)d_in[19];
  const float* lb2 = (const float*)d_in[20];
  const float* lw3 = (const float*)d_in[21];
  const float* lb3 = (const float*)d_in[22];
  float* out = (float*)d_out;

  char* base = (char*)d_ws;
  size_t off = 0;
  auto alloc = [&](size_t bytes) {
    void* p = base + off;
    off = (off + bytes + 255) & ~(size_t)255;
    return p;
  };
  unsigned short* X1b = (unsigned short*)alloc((size_t)N_NODES * 128 * 2);
  unsigned short* Gb  = (unsigned short*)alloc((size_t)N_NODES * 128 * 2);
  unsigned short* H2b = (unsigned short*)alloc((size_t)KP1 * 128 * 2);
  unsigned short* H3b = (unsigned short*)alloc((size_t)KP2 * 128 * 2);
  unsigned short* H4b = (unsigned short*)alloc((size_t)KP3 * 128 * 2);
  int*      cntA   = (int*)alloc((size_t)N_NODES * 4);
  int*      cntB   = (int*)alloc((size_t)KP1 * 4);
  int*      incl   = (int*)alloc((size_t)N_NODES * 4);
  int*      bsum   = (int*)alloc(512 * 4);
  int*      rowstart = (int*)alloc((size_t)(N_NODES + 1) * 4);
  int*      ptr    = (int*)alloc((size_t)N_NODES * 4);
  int*      csr    = (int*)alloc((size_t)N_EDGES * 4);
  float*    xw     = (float*)alloc((size_t)N_NODES * 4);
  float*    score  = (float*)alloc((size_t)N_NODES * 4);
  unsigned* keys   = (unsigned*)alloc((size_t)N_NODES * 4);
  int*      rank   = (int*)alloc((size_t)N_NODES * 4);
  int*      src2   = (int*)alloc((size_t)N_EDGES * 4);
  int*      dst2   = (int*)alloc((size_t)N_EDGES * 4);
  int*      ev2    = (int*)alloc((size_t)N_EDGES * 4);
  unsigned* pgt    = (unsigned*)alloc(512 * 4);
  unsigned* peq    = (unsigned*)alloc(512 * 4);
  unsigned* hist   = (unsigned*)alloc(256 * 4);
  unsigned* state  = (unsigned*)alloc(64);
  unsigned* maxacc3 = (unsigned*)alloc(3 * 128 * 4);
  float*    sumacc3 = (float*)alloc(3 * 128 * 4);
  unsigned short* Wt  = (unsigned short*)alloc((size_t)256 * 512 * 2);
  unsigned short* Wt2 = (unsigned short*)alloc((size_t)256 * 128 * 2);
  unsigned short* Wt3 = (unsigned short*)alloc((size_t)256 * 128 * 2);

  struct Layer {
    const void* H; int n; int K; int kout;
    const float *bl, *gw, *gb;
    const unsigned short* Wt;
    unsigned short* Hout;
    int* cnt;        // this layer's in-degree buffer (ping-pong)
    int* cnt_next;   // next layer's buffer to zero
    int n_next;
  };
  Layer L[3] = {
    { x,   N_NODES, F_IN, KP1, b1l, g1w, g1b, Wt,  H2b, cntA, cntB, KP1 },
    { H2b, KP1,     NHID, KP2, b2l, g2w, g2b, Wt2, H3b, cntB, cntA, KP2 },
    { H3b, KP2,     NHID, KP3, b3l, g3w, g3b, Wt3, H4b, cntA, nullptr, 0 },
  };

  // prep all three layers' bf16 weights; zeroes cnt0 + hist
  wt_prep<<<12, 256, 0, stream>>>(w1l, w1r, w2l, w2r, w3l, w3r, Wt, Wt2, Wt3, cntA, hist);

  for (int l = 0; l < 3; ++l) {
    const Layer& P = L[l];
    const int n = P.n;
    const int nb = (n + 255) / 256;
    const bool small = (n <= 4000);   // single-block paths: small n only
    const int* esrc = (l == 0) ? ei            : src2;
    const int* edst = (l == 0) ? ei + N_EDGES  : dst2;
    const int* eev  = (l == 0) ? (const int*)nullptr : ev2;

    // dual projections via MFMA (no-LDS direct) + fused edge histogram +
    // fused prev-layer readout
    {
      int nbA = (n + 127) / 128;
      int grid = nbA + HISTB + (l > 0 ? RDB : 0);
      gemm_mfma<<<dim3(grid), 512, 0, stream>>>(
          P.H, (l > 0) ? 1 : 0, P.Wt, X1b, Gb, n, P.K, nbA, edst, eev, P.cnt,
          (l > 0) ? L[l - 1].Hout : (const unsigned short*)nullptr,
          (l > 0) ? L[l - 1].kout : 0,
          maxacc3 + (l > 0 ? (l - 1) : 0) * 128,
          sumacc3 + (l > 0 ? (l - 1) : 0) * 128);
    }

    // CSR offsets
    if (small) {
      csr_scan_one<<<1, 1024, 0, stream>>>(P.cnt, n, rowstart, ptr, P.cnt_next, P.n_next);
    } else {
      scan1<<<nb, 256, 0, stream>>>(P.cnt, n, incl, bsum);
      scan2<<<1, 512, 0, stream>>>(bsum, nb);
      scan3<<<nb, 256, 0, stream>>>(P.cnt, incl, bsum, n, rowstart, ptr, P.cnt_next, P.n_next);
    }
    scatter_csr<<<(N_EDGES + 255) / 256, 256, 0, stream>>>(esrc, edst, eev, ptr, csr);
    segsort<<<nb, 256, 0, stream>>>(rowstart, csr, n);

    // fused: G = relu(mean(X1[nbrs]) + bias + G); xw = G . gw
    agg_fin<<<(n * 64 + 255) / 256, 256, 0, stream>>>(X1b, rowstart, csr, P.bl, P.gw, Gb, xw, n);

    // GCN score (also inits top-k state for the multi-block path)
    gcn_score_csr<<<nb, 256, 0, stream>>>(xw, rowstart, csr, P.cnt, P.gb, score, keys, n,
                                          state, P.kout);

    // top-k + rank (both paths also zero this layer's readout accumulators)
    if (small) {
      select_one<<<1, 1024, 0, stream>>>(keys, n, P.kout, rank,
                                         maxacc3 + l * 128, sumacc3 + l * 128);
    } else {
      int hb = nb < 256 ? nb : 256;
      for (int p = 0; p < 4; ++p) {
        int shift = 24 - 8 * p;
        unsigned mask = (p == 0) ? 0u : (0xFFFFFFFFu << (shift + 8));
        topk_hist<<<hb, 256, 0, stream>>>(keys, n, state, mask, shift, hist);
        topk_pick<<<1, 256, 0, stream>>>(state, hist, shift);
      }
      scanA<<<nb, 256, 0, stream>>>(keys, n, state, pgt, peq);
      scanB<<<1, 512, 0, stream>>>(pgt, peq, nb, maxacc3 + l * 128, sumacc3 + l * 128);
      scanC<<<nb, 256, 0, stream>>>(keys, n, state, pgt, peq, P.kout, rank);
    }

    // pool + (tail) relabel; readout of this layer happens in NEXT gemm's tail
    int mode = (l == 0) ? 0 : (l == 1 ? 1 : 2);
    int nbP = (n * 32 + 255) / 256;
    int grid = nbP + (mode < 2 ? RELB : 0);
    pool_rel<<<grid, 256, 0, stream>>>(Gb, score, rank, P.Hout, n, nbP, mode,
                                       ei, src2, dst2, ev2);
  }

  readout_reduce<<<64, 128, 0, stream>>>(H4b, KP3, maxacc3 + 2 * 128, sumacc3 + 2 * 128);
  head_kernel<<<1, 256, 0, stream>>>(maxacc3, sumacc3, lw1, lb1, lw2, lb2, lw3, lb3, out);
}

// Round 16
// 415.495 us; speedup vs baseline: 1.4297x; 1.4297x over previous
//
#include <hip/hip_runtime.h>
#include <hip/hip_bf16.h>
#include <cstdint>
#include <cstddef>

#define N_NODES 100000
#define N_EDGES 500000
#define F_IN    512
#define NHID    128
#define KP1     20000
#define KP2     4000
#define KP3     800
#define GDIM    32
#define NCLS    3
#define HISTB   128   // tail blocks fused into the GEMMs for edge histogram
#define RDB     64    // tail blocks fused into the GEMMs for prev-layer readout
#define RELB    768   // tail blocks fused into pool dispatch for edge relabel

typedef __attribute__((ext_vector_type(8))) short bf16x8;
typedef __attribute__((ext_vector_type(4))) float f32x4;

// ---------- helpers ----------
static __device__ __forceinline__ unsigned enc_f(float f) {
  unsigned u = __float_as_uint(f);
  return (u & 0x80000000u) ? ~u : (u | 0x80000000u);   // monotonic float->uint
}
static __device__ __forceinline__ float dec_f(unsigned u) {
  unsigned v = (u & 0x80000000u) ? (u & 0x7FFFFFFFu) : ~u;
  return __uint_as_float(v);
}
static __device__ __forceinline__ unsigned short f2bf(float f) {  // RNE f32->bf16
  unsigned u = __float_as_uint(f);
  return (unsigned short)((u + 0x7FFFu + ((u >> 16) & 1u)) >> 16);
}
static __device__ __forceinline__ unsigned pk2(float a, float b) {
  return (unsigned)f2bf(a) | ((unsigned)f2bf(b) << 16);
}
static __device__ __forceinline__ float bf2f(unsigned short v) {
  return __uint_as_float(((unsigned)v) << 16);
}

// edge-histogram tail (shared by the GEMM): grid-stride atomics into cnt
static __device__ __forceinline__ void hist_tail(int hb, int t, int nthreads,
                                                 const int* __restrict__ dst,
                                                 const int* __restrict__ ev,
                                                 int* __restrict__ cnt) {
  for (int e = hb * nthreads + t; e < N_EDGES; e += HISTB * nthreads) {
    if (ev && !ev[e]) continue;
    atomicAdd(cnt + dst[e], 1);
  }
}

// ---------- W prep: bf16-transposed weights for ALL three layers ----------
__global__ __launch_bounds__(256) void wt_prep(const float* __restrict__ w1l,
                                               const float* __restrict__ w1r,
                                               const float* __restrict__ w2l,
                                               const float* __restrict__ w2r,
                                               const float* __restrict__ w3l,
                                               const float* __restrict__ w3r,
                                               unsigned short* __restrict__ Wt,
                                               unsigned short* __restrict__ Wt2,
                                               unsigned short* __restrict__ Wt3,
                                               int* __restrict__ cnt0,
                                               unsigned* __restrict__ hist) {
  __shared__ unsigned short T[128][130];
  int blk = blockIdx.x;
  int t = threadIdx.x;
  if (blk == 0) hist[t] = 0u;
  for (int i = blk * 256 + t; i < N_NODES; i += (int)gridDim.x * 256) cnt0[i] = 0;

  const float* W;
  unsigned short* Wo;
  int mat, k0, KW;
  if (blk < 8) {
    mat = blk >> 2; k0 = (blk & 3) * 128; KW = 512;
    W = mat ? w1r : w1l; Wo = Wt;
  } else if (blk < 10) {
    mat = blk - 8; k0 = 0; KW = 128;
    W = mat ? w2r : w2l; Wo = Wt2;
  } else {
    mat = blk - 10; k0 = 0; KW = 128;
    W = mat ? w3r : w3l; Wo = Wt3;
  }
  for (int q = 0; q < 64; ++q) {
    int idx = q * 256 + t;
    int r = idx >> 7, c = idx & 127;
    T[r][c] = f2bf(W[(size_t)(k0 + r) * 128 + c]);
  }
  __syncthreads();
  int nn = t & 127;
  int kc = (t >> 7) * 64;
  for (int j8 = 0; j8 < 8; ++j8) {
    uint4 w;
    int kb = kc + j8 * 8;
    w.x = (unsigned)T[kb + 0][nn] | ((unsigned)T[kb + 1][nn] << 16);
    w.y = (unsigned)T[kb + 2][nn] | ((unsigned)T[kb + 3][nn] << 16);
    w.z = (unsigned)T[kb + 4][nn] | ((unsigned)T[kb + 5][nn] << 16);
    w.w = (unsigned)T[kb + 6][nn] | ((unsigned)T[kb + 7][nn] << 16);
    *reinterpret_cast<uint4*>(Wo + ((size_t)(mat * 128 + nn) * KW + k0 + kb)) = w;
  }
}

// ---------- dual GEMM via MFMA (all layers): X1(bf16)=A@Wl, G(bf16)=A@Wr ----------
// BM=128, 512-thread blocks, LDS-staged (proven fastest across 6 variants).
// A is f32 (layer 1) or bf16 (layers 2/3). Tail blocks: edge histogram, then
// (optional) previous layer's readout (same dependency level as the GEMM input).
__global__ __launch_bounds__(512) void gemm_mfma(const void* __restrict__ Ain, int aBf16,
                                                 const unsigned short* __restrict__ Wt,
                                                 unsigned short* __restrict__ O1b,
                                                 unsigned short* __restrict__ Gb,
                                                 int n, int K, int nbA,
                                                 const int* __restrict__ edst,
                                                 const int* __restrict__ eev,
                                                 int* __restrict__ cnt,
                                                 const unsigned short* __restrict__ Hprev,
                                                 int kprev,
                                                 unsigned* __restrict__ maxaccP,
                                                 float* __restrict__ sumaccP) {
  __shared__ unsigned short Alds[128 * 64];   // [row][k] bf16, XOR-swizzled
  __shared__ float red[4][128];               // readout-tail scratch
  const int t = threadIdx.x;
  if ((int)blockIdx.x >= nbA + HISTB) {
    // previous-layer readout tail (64 blocks); acc was zeroed in select/scanB(prev)
    int hb = blockIdx.x - nbA - HISTB;
    int f = t & 127, rg = t >> 7;
    float m = -INFINITY, s = 0.f;
    for (int r = hb * 4 + rg; r < kprev; r += RDB * 4) {
      float v = bf2f(Hprev[(size_t)r * 128 + f]);
      m = fmaxf(m, v); s += v;
    }
    red[rg][f] = m;
    __syncthreads();
    if (t < 128) {
      float mm = fmaxf(fmaxf(red[0][t], red[1][t]), fmaxf(red[2][t], red[3][t]));
      atomicMax(maxaccP + t, enc_f(mm));
    }
    __syncthreads();
    red[rg][f] = s;
    __syncthreads();
    if (t < 128) {
      float ss = red[0][t] + red[1][t] + red[2][t] + red[3][t];
      atomicAdd(sumaccP + t, ss);
    }
    return;
  }
  if ((int)blockIdx.x >= nbA) {
    hist_tail(blockIdx.x - nbA, t, 512, edst, eev, cnt);
    return;
  }
  const int wave = t >> 6;
  const int lane = t & 63;
  const int wr = wave >> 2;       // 0..1 : 64-row group
  const int wc = wave & 3;        // 0..3 : 64-col group (of 256)
  const int l15 = lane & 15, l4 = lane >> 4;
  const int bm = blockIdx.x * 128;
  f32x4 zero = {0.f, 0.f, 0.f, 0.f};
  f32x4 acc[4][4];
#pragma unroll
  for (int i = 0; i < 4; ++i)
#pragma unroll
    for (int j = 0; j < 4; ++j) acc[i][j] = zero;

  const int sr = t >> 2;            // staging row 0..127
  const int skc = (t & 3) * 16;     // staging k chunk
  const int sgr = bm + sr;
  const float* apf = (const float*)Ain + (size_t)sgr * K + skc;
  const unsigned short* apb = (const unsigned short*)Ain + (size_t)sgr * K + skc;
  const unsigned sbase = sr * 128 + skc * 2;
  const unsigned ssw = (sr & 7) << 4;

  for (int k0 = 0; k0 < K; k0 += 64) {
    __syncthreads();
    if (aBf16) {
      uint4 w0 = make_uint4(0u, 0u, 0u, 0u), w1 = make_uint4(0u, 0u, 0u, 0u);
      if (sgr < n) {
        w0 = *reinterpret_cast<const uint4*>(apb + k0);
        w1 = *reinterpret_cast<const uint4*>(apb + k0 + 8);
      }
      *reinterpret_cast<uint4*>((char*)Alds + (sbase ^ ssw)) = w0;
      *reinterpret_cast<uint4*>((char*)Alds + ((sbase + 16) ^ ssw)) = w1;
    } else {
      float4 v0, v1, v2, v3;
      if (sgr < n) {
        v0 = *reinterpret_cast<const float4*>(apf + k0);
        v1 = *reinterpret_cast<const float4*>(apf + k0 + 4);
        v2 = *reinterpret_cast<const float4*>(apf + k0 + 8);
        v3 = *reinterpret_cast<const float4*>(apf + k0 + 12);
      } else {
        v0 = v1 = v2 = v3 = make_float4(0.f, 0.f, 0.f, 0.f);
      }
      uint4 w0, w1;
      w0.x = pk2(v0.x, v0.y); w0.y = pk2(v0.z, v0.w);
      w0.z = pk2(v1.x, v1.y); w0.w = pk2(v1.z, v1.w);
      w1.x = pk2(v2.x, v2.y); w1.y = pk2(v2.z, v2.w);
      w1.z = pk2(v3.x, v3.y); w1.w = pk2(v3.z, v3.w);
      *reinterpret_cast<uint4*>((char*)Alds + (sbase ^ ssw)) = w0;
      *reinterpret_cast<uint4*>((char*)Alds + ((sbase + 16) ^ ssw)) = w1;
    }
    __syncthreads();
#pragma unroll
    for (int kk = 0; kk < 2; ++kk) {
      bf16x8 af[4], bfr[4];
#pragma unroll
      for (int fr = 0; fr < 4; ++fr) {
        int row = wr * 64 + fr * 16 + l15;
        unsigned ba = (unsigned)(row * 128 + kk * 64 + l4 * 16) ^ ((unsigned)(row & 7) << 4);
        af[fr] = *reinterpret_cast<const bf16x8*>((const char*)Alds + ba);
      }
#pragma unroll
      for (int fn = 0; fn < 4; ++fn) {
        int col = wc * 64 + fn * 16 + l15;
        bfr[fn] = *reinterpret_cast<const bf16x8*>(Wt + ((size_t)col * K + k0 + kk * 32 + l4 * 8));
      }
#pragma unroll
      for (int fr = 0; fr < 4; ++fr)
#pragma unroll
        for (int fn = 0; fn < 4; ++fn)
          acc[fr][fn] = __builtin_amdgcn_mfma_f32_16x16x32_bf16(af[fr], bfr[fn], acc[fr][fn], 0, 0, 0);
    }
  }

#pragma unroll
  for (int fr = 0; fr < 4; ++fr) {
#pragma unroll
    for (int fn = 0; fn < 4; ++fn) {
      int colg = wc * 64 + fn * 16 + l15;
      int col = colg & 127;
      int row0 = bm + wr * 64 + fr * 16 + l4 * 4;
#pragma unroll
      for (int r2 = 0; r2 < 4; ++r2) {
        int gr = row0 + r2;
        if (gr < n) {
          unsigned short bv = f2bf(acc[fr][fn][r2]);
          if (colg < 128) O1b[(size_t)gr * 128 + col] = bv;
          else            Gb [(size_t)gr * 128 + col] = bv;
        }
      }
    }
  }
}

// ---------- CSR build: multi-dispatch path (large n) ----------
__global__ void scan1(const int* __restrict__ cnt, int n,
                      int* __restrict__ incl, int* __restrict__ bsum) {
  __shared__ int sh[256];
  int t = threadIdx.x, i = blockIdx.x * 256 + t;
  int v = (i < n) ? cnt[i] : 0;
  sh[t] = v; __syncthreads();
  for (int o = 1; o < 256; o <<= 1) {
    int a = (t >= o) ? sh[t - o] : 0;
    __syncthreads(); sh[t] += a; __syncthreads();
  }
  if (i < n) incl[i] = sh[t];
  if (t == 255) bsum[blockIdx.x] = sh[255];
}

__global__ void scan2(int* __restrict__ bsum, int nb) {
  __shared__ int sh[512];
  int t = threadIdx.x;
  int v = (t < nb) ? bsum[t] : 0;
  sh[t] = v; __syncthreads();
  for (int o = 1; o < 512; o <<= 1) {
    int a = (t >= o) ? sh[t - o] : 0;
    __syncthreads(); sh[t] += a; __syncthreads();
  }
  if (t < nb) bsum[t] = sh[t] - v;   // exclusive
}

__global__ void scan3(const int* __restrict__ cnt, const int* __restrict__ incl,
                      const int* __restrict__ bsum, int n,
                      int* __restrict__ rowstart, int* __restrict__ ptr,
                      int* __restrict__ cnt_next, int n_next) {
  int i = blockIdx.x * 256 + threadIdx.x;
  if (i < n_next) cnt_next[i] = 0;
  if (i >= n) return;
  int excl = incl[i] - cnt[i] + bsum[blockIdx.x];
  rowstart[i] = excl; ptr[i] = excl;
  if (i == n - 1) rowstart[n] = excl + cnt[i];
}

// ---------- CSR offsets: single-block path (small n only) ----------
__global__ __launch_bounds__(1024) void csr_scan_one(const int* __restrict__ cnt, int n,
                                                     int* __restrict__ rowstart,
                                                     int* __restrict__ ptr,
                                                     int* __restrict__ cnt_next, int n_next) {
  __shared__ int sg[1024];
  const int t = threadIdx.x;
  for (int i = t; i < n_next; i += 1024) cnt_next[i] = 0;
  const int chunk = (n + 1023) >> 10;
  const int i0 = t * chunk;
  const int i1 = (i0 + chunk < n) ? i0 + chunk : n;
  int c = 0;
  for (int i = i0; i < i1; ++i) c += cnt[i];
  sg[t] = c;
  __syncthreads();
  for (int o = 1; o < 1024; o <<= 1) {
    int a = (t >= o) ? sg[t - o] : 0;
    __syncthreads();
    sg[t] += a;
    __syncthreads();
  }
  int excl = sg[t] - c;
  for (int i = i0; i < i1; ++i) {
    rowstart[i] = excl; ptr[i] = excl;
    excl += cnt[i];
  }
  if (t == 1023) rowstart[n] = sg[1023];
}

__global__ void scatter_csr(const int* __restrict__ src, const int* __restrict__ dst,
                            const int* __restrict__ ev, int* __restrict__ ptr,
                            int* __restrict__ csr_src) {
  int e = blockIdx.x * 256 + threadIdx.x;
  if (e >= N_EDGES) return;
  if (ev && !ev[e]) return;
  int p = atomicAdd(ptr + dst[e], 1);
  csr_src[p] = src[e];
}

// canonical order inside each segment -> deterministic f32 sums
__global__ void segsort(const int* __restrict__ rowstart, int* __restrict__ csr, int n) {
  int i = blockIdx.x * 256 + threadIdx.x;
  if (i >= n) return;
  int b = rowstart[i], e = rowstart[i + 1];
  for (int j = b + 1; j < e; ++j) {
    int v = csr[j], k = j - 1;
    while (k >= b && csr[k] > v) { csr[k + 1] = csr[k]; --k; }
    csr[k + 1] = v;
  }
}

// ---------- fused aggregation + GCN xw (bf16; 4 independent gathers in flight,
//            accumulation stays in strict index order -> bit-identical) ----------
__global__ void agg_fin(const unsigned short* __restrict__ X1b, const int* __restrict__ rowstart,
                        const int* __restrict__ csr, const float* __restrict__ bias,
                        const float* __restrict__ gw,
                        unsigned short* __restrict__ Gb, float* __restrict__ xw, int n) {
  int wid = (blockIdx.x * 256 + threadIdx.x) >> 6;
  if (wid >= n) return;
  int lane = threadIdx.x & 63;
  int b = rowstart[wid], e = rowstart[wid + 1];
  float sx = 0.f, sy = 0.f;
  int p = b;
  for (; p + 3 < e; p += 4) {
    int s0 = csr[p], s1 = csr[p + 1], s2 = csr[p + 2], s3 = csr[p + 3];
    unsigned v0 = *reinterpret_cast<const unsigned*>(X1b + (size_t)s0 * 128 + lane * 2);
    unsigned v1 = *reinterpret_cast<const unsigned*>(X1b + (size_t)s1 * 128 + lane * 2);
    unsigned v2 = *reinterpret_cast<const unsigned*>(X1b + (size_t)s2 * 128 + lane * 2);
    unsigned v3 = *reinterpret_cast<const unsigned*>(X1b + (size_t)s3 * 128 + lane * 2);
    sx += bf2f((unsigned short)(v0 & 0xFFFFu)); sy += bf2f((unsigned short)(v0 >> 16));
    sx += bf2f((unsigned short)(v1 & 0xFFFFu)); sy += bf2f((unsigned short)(v1 >> 16));
    sx += bf2f((unsigned short)(v2 & 0xFFFFu)); sy += bf2f((unsigned short)(v2 >> 16));
    sx += bf2f((unsigned short)(v3 & 0xFFFFu)); sy += bf2f((unsigned short)(v3 >> 16));
  }
  for (; p < e; ++p) {
    int s0 = csr[p];
    unsigned v0 = *reinterpret_cast<const unsigned*>(X1b + (size_t)s0 * 128 + lane * 2);
    sx += bf2f((unsigned short)(v0 & 0xFFFFu));
    sy += bf2f((unsigned short)(v0 >> 16));
  }
  int c = e - b; if (c < 1) c = 1;
  float inv = 1.f / (float)c;
  float2 bi = *reinterpret_cast<const float2*>(bias + lane * 2);
  unsigned gv = *reinterpret_cast<const unsigned*>(Gb + (size_t)wid * 128 + lane * 2);
  float gx = bf2f((unsigned short)(gv & 0xFFFFu));
  float gy = bf2f((unsigned short)(gv >> 16));
  float2 o = make_float2(fmaxf(sx * inv + bi.x + gx, 0.f),
                         fmaxf(sy * inv + bi.y + gy, 0.f));
  *reinterpret_cast<unsigned*>(Gb + (size_t)wid * 128 + lane * 2) = pk2(o.x, o.y);
  float2 gwv = *reinterpret_cast<const float2*>(gw + lane * 2);
  float s = o.x * gwv.x + o.y * gwv.y;
  for (int off = 32; off; off >>= 1) s += __shfl_down(s, off);
  if (lane == 0) xw[wid] = s;
}

// ---------- GCN score (4-deep unroll; also initializes top-k radix state) ----------
__global__ void gcn_score_csr(const float* __restrict__ xw, const int* __restrict__ rowstart,
                              const int* __restrict__ csr, const int* __restrict__ cnt,
                              const float* __restrict__ gb,
                              float* __restrict__ score, unsigned* __restrict__ keys, int n,
                              unsigned* __restrict__ state, int kout) {
  int i = blockIdx.x * 256 + threadIdx.x;
  if (i == 0) { state[0] = 0u; state[1] = (unsigned)kout; }
  if (i >= n) return;
  int b = rowstart[i], e = rowstart[i + 1];
  float di = rsqrtf((float)(e - b) + 1.f);
  float s = 0.f;
  int p = b;
  for (; p + 3 < e; p += 4) {
    int s0 = csr[p], s1 = csr[p + 1], s2 = csr[p + 2], s3 = csr[p + 3];
    float x0 = xw[s0], x1 = xw[s1], x2 = xw[s2], x3 = xw[s3];
    float c0 = (float)cnt[s0], c1 = (float)cnt[s1];
    float c2 = (float)cnt[s2], c3 = (float)cnt[s3];
    s += x0 * rsqrtf(c0 + 1.f);
    s += x1 * rsqrtf(c1 + 1.f);
    s += x2 * rsqrtf(c2 + 1.f);
    s += x3 * rsqrtf(c3 + 1.f);
  }
  for (; p < e; ++p) {
    int s0 = csr[p];
    s += xw[s0] * rsqrtf((float)cnt[s0] + 1.f);
  }
  float sc = s * di + xw[i] * di * di + gb[0];
  score[i] = sc;
  keys[i] = enc_f(sc);
}

// ---------- top-k radix select, multi-block path (large n) ----------
__global__ void topk_hist(const unsigned* __restrict__ keys, int n,
                          const unsigned* __restrict__ state, unsigned mask, int shift,
                          unsigned* __restrict__ hist) {
  __shared__ unsigned h[256];
  int t = threadIdx.x;
  h[t] = 0u;
  __syncthreads();
  unsigned pref = state[0];
  for (int i = blockIdx.x * 256 + t; i < n; i += gridDim.x * 256) {
    unsigned k = keys[i];
    if ((k & mask) == pref) atomicAdd(&h[(k >> shift) & 0xFFu], 1u);
  }
  __syncthreads();
  unsigned hv = h[t];
  if (hv) atomicAdd(&hist[t], hv);
}

__global__ void topk_pick(unsigned* state, unsigned* hist, int shift) {
  __shared__ unsigned h[256], a[256];
  int t = threadIdx.x;
  unsigned hv = hist[t];
  hist[t] = 0;                      // clear for next pass
  h[t] = hv;
  __syncthreads();
  a[t] = h[255 - t];                // reversed for suffix-sum
  __syncthreads();
  for (int o = 1; o < 256; o <<= 1) {
    unsigned v = (t >= o) ? a[t - o] : 0u;
    __syncthreads();
    a[t] += v;
    __syncthreads();
  }
  unsigned krem = state[1];
  unsigned Sb  = a[255 - t];
  unsigned Sb1 = (t == 255) ? 0u : a[255 - (t + 1)];
  if (Sb >= krem && Sb1 < krem) {
    state[0] |= ((unsigned)t) << shift;
    state[1] = krem - Sb1;
  }
}

// ---------- deterministic compaction (rank assignment), multi-block path ----------
__global__ void scanA(const unsigned* __restrict__ keys, int n,
                      const unsigned* __restrict__ state,
                      unsigned* __restrict__ pgt, unsigned* __restrict__ peq) {
  __shared__ unsigned sg[256], se[256];
  int t = threadIdx.x;
  int i = blockIdx.x * 256 + t;
  unsigned kth = state[0];
  unsigned g = 0, e = 0;
  if (i < n) { unsigned k = keys[i]; g = (k > kth); e = (k == kth); }
  sg[t] = g; se[t] = e;
  __syncthreads();
  for (int s = 128; s; s >>= 1) {
    if (t < s) { sg[t] += sg[t + s]; se[t] += se[t + s]; }
    __syncthreads();
  }
  if (t == 0) { pgt[blockIdx.x] = sg[0]; peq[blockIdx.x] = se[0]; }
}

// also zeroes this layer's readout accumulators (runs before readout)
__global__ void scanB(unsigned* pgt, unsigned* peq, int nb,
                      unsigned* __restrict__ maxacc, float* __restrict__ sumacc) {
  __shared__ unsigned a[512], b[512];
  int t = threadIdx.x;
  if (t < 128) { maxacc[t] = 0u; sumacc[t] = 0.f; }
  unsigned og = (t < nb) ? pgt[t] : 0u;
  unsigned oe = (t < nb) ? peq[t] : 0u;
  a[t] = og; b[t] = oe;
  __syncthreads();
  for (int o = 1; o < 512; o <<= 1) {
    unsigned av = (t >= o) ? a[t - o] : 0u;
    unsigned bv = (t >= o) ? b[t - o] : 0u;
    __syncthreads();
    a[t] += av; b[t] += bv;
    __syncthreads();
  }
  if (t < nb) { pgt[t] = a[t] - og; peq[t] = b[t] - oe; }   // exclusive
}

__global__ void scanC(const unsigned* __restrict__ keys, int n,
                      const unsigned* __restrict__ state,
                      const unsigned* __restrict__ pgt, const unsigned* __restrict__ peq,
                      int K, int* __restrict__ rank) {
  __shared__ unsigned sg[256], se[256];
  int t = threadIdx.x;
  int i = blockIdx.x * 256 + t;
  unsigned kth = state[0], krem = state[1];
  unsigned g = 0, e = 0;
  if (i < n) { unsigned k = keys[i]; g = (k > kth); e = (k == kth); }
  sg[t] = g; se[t] = e;
  __syncthreads();
  for (int o = 1; o < 256; o <<= 1) {
    unsigned av = (t >= o) ? sg[t - o] : 0u;
    unsigned bv = (t >= o) ? se[t - o] : 0u;
    __syncthreads();
    sg[t] += av; se[t] += bv;
    __syncthreads();
  }
  if (i < n) {
    int r = -1;
    unsigned n_gt = (unsigned)K - krem;
    if (g) r = (int)(pgt[blockIdx.x] + sg[t] - 1);
    else if (e) {
      unsigned pe = peq[blockIdx.x] + se[t] - 1;
      if (pe < krem) r = (int)(n_gt + pe);
    }
    rank[i] = r;
  }
}

// ---------- single-block top-k + rank (small n ONLY) ----------
__global__ __launch_bounds__(1024) void select_one(const unsigned* __restrict__ keys, int n,
                                                   int K, int* __restrict__ rank,
                                                   unsigned* __restrict__ maxacc,
                                                   float* __restrict__ sumacc) {
  __shared__ unsigned h[256], a[256];
  __shared__ unsigned sg[1024], se[1024];
  __shared__ unsigned s_pref, s_krem;
  const int t = threadIdx.x;
  if (t < 128) { maxacc[t] = 0u; sumacc[t] = 0.f; }
  if (t == 0) { s_pref = 0u; s_krem = (unsigned)K; }
  __syncthreads();

#pragma unroll
  for (int p = 0; p < 4; ++p) {
    const int shift = 24 - 8 * p;
    const unsigned mask = (p == 0) ? 0u : (0xFFFFFFFFu << (shift + 8));
    if (t < 256) h[t] = 0u;
    __syncthreads();
    unsigned pref = s_pref;
    for (int i = t; i < n; i += 1024) {
      unsigned k = keys[i];
      if ((k & mask) == pref) atomicAdd(&h[(k >> shift) & 0xFFu], 1u);
    }
    __syncthreads();
    if (t < 256) a[t] = h[255 - t];   // reversed for suffix-sum
    __syncthreads();
    for (int o = 1; o < 256; o <<= 1) {
      unsigned v = (t >= o && t < 256) ? a[t - o] : 0u;
      __syncthreads();
      if (t < 256) a[t] += v;
      __syncthreads();
    }
    unsigned krem = s_krem;
    __syncthreads();
    if (t < 256) {
      unsigned Sb  = a[255 - t];
      unsigned Sb1 = (t == 255) ? 0u : a[255 - (t + 1)];
      if (Sb >= krem && Sb1 < krem) {
        s_pref |= ((unsigned)t) << shift;
        s_krem = krem - Sb1;
      }
    }
    __syncthreads();
  }

  // rank assignment, index order (contiguous per-thread chunks)
  const unsigned kth = s_pref;
  const unsigned krem = s_krem;
  const unsigned n_gt = (unsigned)K - krem;
  const int chunk = (n + 1023) >> 10;
  const int i0 = t * chunk;
  const int i1 = (i0 + chunk < n) ? i0 + chunk : n;
  unsigned cg = 0, ce = 0;
  for (int i = i0; i < i1; ++i) {
    unsigned k = keys[i];
    cg += (k > kth); ce += (k == kth);
  }
  sg[t] = cg; se[t] = ce;
  __syncthreads();
  for (int o = 1; o < 1024; o <<= 1) {
    unsigned ag = (t >= o) ? sg[t - o] : 0u;
    unsigned ae = (t >= o) ? se[t - o] : 0u;
    __syncthreads();
    sg[t] += ag; se[t] += ae;
    __syncthreads();
  }
  unsigned rg = sg[t] - cg;   // exclusive prefix of > count
  unsigned re = se[t] - ce;   // exclusive prefix of == count
  for (int i = i0; i < i1; ++i) {
    unsigned k = keys[i];
    int r = -1;
    if (k > kth) {
      r = (int)(rg++);
    } else if (k == kth) {
      unsigned pe = re++;
      if (pe < krem) r = (int)(n_gt + pe);
    }
    rank[i] = r;
  }
}

// ---------- pooling (bf16 G -> bf16 Hout) + (tail) edge relabel ----------
__global__ void pool_rel(const unsigned short* __restrict__ Gb, const float* __restrict__ score,
                         const int* __restrict__ rank, unsigned short* __restrict__ Houtb, int n,
                         int nbP, int mode,
                         const int* __restrict__ ei,
                         int* __restrict__ src2, int* __restrict__ dst2,
                         int* __restrict__ ev2) {
  const int t = threadIdx.x;
  if ((int)blockIdx.x >= nbP) {
    int hb = blockIdx.x - nbP;
    if (mode == 0) {
      for (int e = hb * 256 + t; e < N_EDGES; e += RELB * 256) {
        int s = ei[e], d = ei[N_EDGES + e];
        int rs = rank[s], rd = rank[d];
        int valid = (rs >= 0) & (rd >= 0);
        src2[e] = rs > 0 ? rs : 0;
        dst2[e] = rd > 0 ? rd : 0;
        ev2[e] = valid;
      }
    } else if (mode == 1) {
      for (int e = hb * 256 + t; e < N_EDGES; e += RELB * 256) {
        if (!ev2[e]) continue;
        int s = src2[e], d = dst2[e];
        int rs = rank[s], rd = rank[d];
        int valid = (rs >= 0) & (rd >= 0);
        src2[e] = rs > 0 ? rs : 0;
        dst2[e] = rd > 0 ? rd : 0;
        ev2[e] = valid;
      }
    }
    return;
  }
  int gid = blockIdx.x * 256 + t;
  int i = gid >> 5;
  if (i >= n) return;
  int r = rank[i];
  if (r < 0) return;
  int q = gid & 31;
  float tv = tanhf(score[i]);
  uint2 v = *reinterpret_cast<const uint2*>(Gb + (size_t)i * 128 + q * 4);
  float a0 = bf2f((unsigned short)(v.x & 0xFFFFu)) * tv;
  float a1 = bf2f((unsigned short)(v.x >> 16)) * tv;
  float a2 = bf2f((unsigned short)(v.y & 0xFFFFu)) * tv;
  float a3 = bf2f((unsigned short)(v.y >> 16)) * tv;
  uint2 o = make_uint2(pk2(a0, a1), pk2(a2, a3));
  *reinterpret_cast<uint2*>(Houtb + (size_t)r * 128 + q * 4) = o;
}

// ---------- graph readout (bf16 H; used for the LAST layer only) ----------
__global__ void readout_reduce(const unsigned short* __restrict__ Hb, int k,
                               unsigned* __restrict__ maxacc, float* __restrict__ sumacc) {
  int f = threadIdx.x;   // 128
  float m = -INFINITY, s = 0.f;
  for (int r = blockIdx.x; r < k; r += gridDim.x) {
    float v = bf2f(Hb[(size_t)r * 128 + f]);
    m = fmaxf(m, v);
    s += v;
  }
  atomicMax(maxacc + f, enc_f(m));
  atomicAdd(sumacc + f, s);
}

// ---------- head MLP (decodes per-layer readout accumulators directly) ----------
__global__ void head_kernel(const unsigned* __restrict__ maxacc3,
                            const float* __restrict__ sumacc3,
                            const float* __restrict__ lw1, const float* __restrict__ lb1,
                            const float* __restrict__ lw2, const float* __restrict__ lb2,
                            const float* __restrict__ lw3, const float* __restrict__ lb3,
                            float* __restrict__ out) {
  __shared__ float g[256];
  __shared__ float t1[128];
  __shared__ float t2[32];
  int t = threadIdx.x;
  float v;
  if (t < 128) {
    v = dec_f(maxacc3[t]) + dec_f(maxacc3[128 + t]) + dec_f(maxacc3[256 + t]);
  } else {
    int f = t - 128;
    v = sumacc3[f] * (1.f / (float)KP1) + sumacc3[128 + f] * (1.f / (float)KP2) +
        sumacc3[256 + f] * (1.f / (float)KP3);
  }
  g[t] = v;
  __syncthreads();
  if (t < 128) {
    float s = lb1[t];
    for (int j = 0; j < 256; ++j) s += g[j] * lw1[j * 128 + t];
    t1[t] = fmaxf(s, 0.f);
  }
  __syncthreads();
  if (t < 32) {
    float s = lb2[t];
    for (int j = 0; j < 128; ++j) s += t1[j] * lw2[j * 32 + t];
    float v2 = fmaxf(s, 0.f);
    t2[t] = v2;
    out[t] = v2;                // features
  }
  __syncthreads();
  if (t < NCLS) {
    float s = lb3[t];
    for (int j = 0; j < 32; ++j) s += t2[j] * lw3[j * 3 + t];
    out[32 + t] = s;            // logits
  }
}

// ---------- launch ----------
extern "C" void kernel_launch(void* const* d_in, const int* in_sizes, int n_in_,
                              void* d_out, int out_size, void* d_ws, size_t ws_size,
                              hipStream_t stream) {
  (void)in_sizes; (void)n_in_; (void)out_size; (void)ws_size;
  const float* x   = (const float*)d_in[0];
  const int*   ei  = (const int*)d_in[1];
  const float* w1l = (const float*)d_in[2];
  const float* b1l = (const float*)d_in[3];
  const float* w1r = (const float*)d_in[4];
  const float* g1w = (const float*)d_in[5];
  const float* g1b = (const float*)d_in[6];
  const float* w2l = (const float*)d_in[7];
  const float* b2l = (const float*)d_in[8];
  const float* w2r = (const float*)d_in[9];
  const float* g2w = (const float*)d_in[10];
  const float* g2b = (const float*)d_in[11];
  const float* w3l = (const float*)d_in[12];
  const float* b3l = (const float*)d_in[13];
  const float* w3r = (const float*)d_in[14];
  const float* g3w = (const float*)d_in[15];
  const float* g3b = (const float*)d_in[16];
  const float* lw1 = (const float*)d_in[17];
  const float* lb1 = (const float*)d_in[18];
  const float* lw2 = (const float*)d_in[19];
  const float* lb2 = (const float*)d_in[20];
  const float* lw3 = (const float*)d_in[21];
  const float* lb3 = (const float*)d_in[22];
  float* out = (float*)d_out;

  char* base = (char*)d_ws;
  size_t off = 0;
  auto alloc = [&](size_t bytes) {
    void* p = base + off;
    off = (off + bytes + 255) & ~(size_t)255;
    return p;
  };
  unsigned short* X1b = (unsigned short*)alloc((size_t)N_NODES * 128 * 2);
  unsigned short* Gb  = (unsigned short*)alloc((size_t)N_NODES * 128 * 2);
  unsigned short* H2b = (unsigned short*)alloc((size_t)KP1 * 128 * 2);
  unsigned short* H3b = (unsigned short*)alloc((size_t)KP2 * 128 * 2);
  unsigned short* H4b = (unsigned short*)alloc((size_t)KP3 * 128 * 2);
  int*      cntA   = (int*)alloc((size_t)N_NODES * 4);
  int*      cntB   = (int*)alloc((size_t)KP1 * 4);
  int*      incl   = (int*)alloc((size_t)N_NODES * 4);
  int*      bsum   = (int*)alloc(512 * 4);
  int*      rowstart = (int*)alloc((size_t)(N_NODES + 1) * 4);
  int*      ptr    = (int*)alloc((size_t)N_NODES * 4);
  int*      csr    = (int*)alloc((size_t)N_EDGES * 4);
  float*    xw     = (float*)alloc((size_t)N_NODES * 4);
  float*    score  = (float*)alloc((size_t)N_NODES * 4);
  unsigned* keys   = (unsigned*)alloc((size_t)N_NODES * 4);
  int*      rank   = (int*)alloc((size_t)N_NODES * 4);
  int*      src2   = (int*)alloc((size_t)N_EDGES * 4);
  int*      dst2   = (int*)alloc((size_t)N_EDGES * 4);
  int*      ev2    = (int*)alloc((size_t)N_EDGES * 4);
  unsigned* pgt    = (unsigned*)alloc(512 * 4);
  unsigned* peq    = (unsigned*)alloc(512 * 4);
  unsigned* hist   = (unsigned*)alloc(256 * 4);
  unsigned* state  = (unsigned*)alloc(64);
  unsigned* maxacc3 = (unsigned*)alloc(3 * 128 * 4);
  float*    sumacc3 = (float*)alloc(3 * 128 * 4);
  unsigned short* Wt  = (unsigned short*)alloc((size_t)256 * 512 * 2);
  unsigned short* Wt2 = (unsigned short*)alloc((size_t)256 * 128 * 2);
  unsigned short* Wt3 = (unsigned short*)alloc((size_t)256 * 128 * 2);

  struct Layer {
    const void* H; int n; int K; int kout;
    const float *bl, *gw, *gb;
    const unsigned short* Wt;
    unsigned short* Hout;
    int* cnt;        // this layer's in-degree buffer (ping-pong)
    int* cnt_next;   // next layer's buffer to zero
    int n_next;
  };
  Layer L[3] = {
    { x,   N_NODES, F_IN, KP1, b1l, g1w, g1b, Wt,  H2b, cntA, cntB, KP1 },
    { H2b, KP1,     NHID, KP2, b2l, g2w, g2b, Wt2, H3b, cntB, cntA, KP2 },
    { H3b, KP2,     NHID, KP3, b3l, g3w, g3b, Wt3, H4b, cntA, nullptr, 0 },
  };

  // prep all three layers' bf16 weights; zeroes cnt0 + hist
  wt_prep<<<12, 256, 0, stream>>>(w1l, w1r, w2l, w2r, w3l, w3r, Wt, Wt2, Wt3, cntA, hist);

  for (int l = 0; l < 3; ++l) {
    const Layer& P = L[l];
    const int n = P.n;
    const int nb = (n + 255) / 256;
    const bool small = (n <= 4000);   // single-block paths: small n only
    const int* esrc = (l == 0) ? ei            : src2;
    const int* edst = (l == 0) ? ei + N_EDGES  : dst2;
    const int* eev  = (l == 0) ? (const int*)nullptr : ev2;

    // dual projections via MFMA + fused edge histogram + fused prev-layer readout
    {
      int nbA = (n + 127) / 128;
      int grid = nbA + HISTB + (l > 0 ? RDB : 0);
      gemm_mfma<<<dim3(grid), 512, 0, stream>>>(
          P.H, (l > 0) ? 1 : 0, P.Wt, X1b, Gb, n, P.K, nbA, edst, eev, P.cnt,
          (l > 0) ? L[l - 1].Hout : (const unsigned short*)nullptr,
          (l > 0) ? L[l - 1].kout : 0,
          maxacc3 + (l > 0 ? (l - 1) : 0) * 128,
          sumacc3 + (l > 0 ? (l - 1) : 0) * 128);
    }

    // CSR offsets
    if (small) {
      csr_scan_one<<<1, 1024, 0, stream>>>(P.cnt, n, rowstart, ptr, P.cnt_next, P.n_next);
    } else {
      scan1<<<nb, 256, 0, stream>>>(P.cnt, n, incl, bsum);
      scan2<<<1, 512, 0, stream>>>(bsum, nb);
      scan3<<<nb, 256, 0, stream>>>(P.cnt, incl, bsum, n, rowstart, ptr, P.cnt_next, P.n_next);
    }
    scatter_csr<<<(N_EDGES + 255) / 256, 256, 0, stream>>>(esrc, edst, eev, ptr, csr);
    segsort<<<nb, 256, 0, stream>>>(rowstart, csr, n);

    // fused: G = relu(mean(X1[nbrs]) + bias + G); xw = G . gw
    agg_fin<<<(n * 64 + 255) / 256, 256, 0, stream>>>(X1b, rowstart, csr, P.bl, P.gw, Gb, xw, n);

    // GCN score (also inits top-k state for the multi-block path)
    gcn_score_csr<<<nb, 256, 0, stream>>>(xw, rowstart, csr, P.cnt, P.gb, score, keys, n,
                                          state, P.kout);

    // top-k + rank (both paths also zero this layer's readout accumulators)
    if (small) {
      select_one<<<1, 1024, 0, stream>>>(keys, n, P.kout, rank,
                                         maxacc3 + l * 128, sumacc3 + l * 128);
    } else {
      int hb = nb < 256 ? nb : 256;
      for (int p = 0; p < 4; ++p) {
        int shift = 24 - 8 * p;
        unsigned mask = (p == 0) ? 0u : (0xFFFFFFFFu << (shift + 8));
        topk_hist<<<hb, 256, 0, stream>>>(keys, n, state, mask, shift, hist);
        topk_pick<<<1, 256, 0, stream>>>(state, hist, shift);
      }
      scanA<<<nb, 256, 0, stream>>>(keys, n, state, pgt, peq);
      scanB<<<1, 512, 0, stream>>>(pgt, peq, nb, maxacc3 + l * 128, sumacc3 + l * 128);
      scanC<<<nb, 256, 0, stream>>>(keys, n, state, pgt, peq, P.kout, rank);
    }

    // pool + (tail) relabel; readout of this layer happens in NEXT gemm's tail
    int mode = (l == 0) ? 0 : (l == 1 ? 1 : 2);
    int nbP = (n * 32 + 255) / 256;
    int grid = nbP + (mode < 2 ? RELB : 0);
    pool_rel<<<grid, 256, 0, stream>>>(Gb, score, rank, P.Hout, n, nbP, mode,
                                       ei, src2, dst2, ev2);
  }

  readout_reduce<<<64, 128, 0, stream>>>(H4b, KP3, maxacc3 + 2 * 128, sumacc3 + 2 * 128);
  head_kernel<<<1, 256, 0, stream>>>(maxacc3, sumacc3, lw1, lb1, lw2, lb2, lw3, lb3, out);
}